// Round 11
// baseline (345.814 us; speedup 1.0000x reference)
//
#include <hip/hip_runtime.h>
#include <hip/hip_bf16.h>

#define NN 50000
#define EE 800000
#define DD 64
#define LL 4
#define GG 64
#define PJ 16   // pooling sub-blocks per graph
#define NXCD 8
#define DRANGE (NN / NXCD)   // 6250 dst nodes per XCD range

// pure stream: el_all[e] = float4 of (edge_attr[e] . ce[l]) for l=0..3.
// ce recomputed per block (bit-identical sequential loop; proven in R6).
__global__ __launch_bounds__(256) void k_el(const float* __restrict__ ea,
                                            const float* __restrict__ We,
                                            const float* __restrict__ a_e,
                                            float* __restrict__ el_all, int ne) {
    __shared__ float sce[64];
    if (threadIdx.x < 64) {
        int l = threadIdx.x >> 4, k = threadIdx.x & 15;
        float acc = 0.f;
        for (int j = 0; j < 64; ++j)
            acc += We[l * 1024 + k * 64 + j] * a_e[l * 64 + j];
        sce[threadIdx.x] = acc;
    }
    __syncthreads();
    int e = blockIdx.x * 256 + threadIdx.x;
    if (e >= ne) return;
    const float4* p4 = reinterpret_cast<const float4*>(ea + (size_t)e * 16);
    float v[16];
    float4 q;
    q = p4[0]; v[0] = q.x; v[1] = q.y; v[2] = q.z; v[3] = q.w;
    q = p4[1]; v[4] = q.x; v[5] = q.y; v[6] = q.z; v[7] = q.w;
    q = p4[2]; v[8] = q.x; v[9] = q.y; v[10] = q.z; v[11] = q.w;
    q = p4[3]; v[12] = q.x; v[13] = q.y; v[14] = q.z; v[15] = q.w;
    float o[4];
#pragma unroll
    for (int l = 0; l < 4; ++l) {
        float a = 0.f;
#pragma unroll
        for (int k = 0; k < 16; ++k) a = fmaf(v[k], sce[l * 16 + k], a);
        o[l] = a;
    }
    reinterpret_cast<float4*>(el_all)[e] = make_float4(o[0], o[1], o[2], o[3]);
}

// XCD-range-partitioned histogram
__global__ __launch_bounds__(256) void k_hist(const int* __restrict__ dst,
                                              int* __restrict__ counts, int ne) {
    int r = blockIdx.x;
    int e = blockIdx.y * 256 + threadIdx.x;
    if (e >= ne) return;
    int d = dst[e];
    int rlo = r * DRANGE;
    if (d < rlo || d >= rlo + DRANGE) return;
    atomicAdd(&counts[d], 1);
}

// ---------------- CSR build ----------------
__global__ void k_scan1(const int* __restrict__ counts, int* __restrict__ bsum, int n) {
    __shared__ int s[256];
    int i = blockIdx.x * 256 + threadIdx.x;
    s[threadIdx.x] = (i < n) ? counts[i] : 0;
    __syncthreads();
    for (int off = 128; off; off >>= 1) {
        if (threadIdx.x < off) s[threadIdx.x] += s[threadIdx.x + off];
        __syncthreads();
    }
    if (threadIdx.x == 0) bsum[blockIdx.x] = s[0];
}

__global__ void k_scan2(int* __restrict__ bsum, int nb) {  // one block, nb<=256
    __shared__ int s[256];
    int t = threadIdx.x;
    int v = (t < nb) ? bsum[t] : 0;
    s[t] = v;
    __syncthreads();
    for (int off = 1; off < 256; off <<= 1) {
        int x = (t >= off) ? s[t - off] : 0;
        __syncthreads();
        s[t] += x;
        __syncthreads();
    }
    if (t < nb) bsum[t] = s[t] - v;  // exclusive
}

__global__ void k_scan3(const int* __restrict__ counts, const int* __restrict__ bsum,
                        int* __restrict__ row_ptr, int n) {
    __shared__ int s[256];
    int t = threadIdx.x;
    int i = blockIdx.x * 256 + t;
    int v = (i < n) ? counts[i] : 0;
    s[t] = v;
    __syncthreads();
    for (int off = 1; off < 256; off <<= 1) {
        int x = (t >= off) ? s[t - off] : 0;
        __syncthreads();
        s[t] += x;
        __syncthreads();
    }
    if (i < n) row_ptr[i] = s[t] - v + bsum[blockIdx.x];
}

// XCD-range-partitioned scatter
__global__ __launch_bounds__(256) void k_fill(const int* __restrict__ dst,
                                              const int* __restrict__ row_ptr,
                                              int* __restrict__ cursor,
                                              int* __restrict__ csr_eid, int ne) {
    int r = blockIdx.x;
    int e = blockIdx.y * 256 + threadIdx.x;
    if (e >= ne) return;
    int d = dst[e];
    int rlo = r * DRANGE;
    if (d < rlo || d >= rlo + DRANGE) return;
    int pos = row_ptr[d] + atomicAdd(&cursor[d], 1);
    csr_eid[pos] = e;
}

// deterministic row order (sort by eid) via rank computation.
// Fast path: 2 nodes per wave (two 32-lane groups), uniform-length rank loop
// with MAX-sentinel padding (identical ranks as the 64-lane version).
__global__ __launch_bounds__(256) void k_sortperm(int* __restrict__ csr_eid,
                                                  const int* __restrict__ e_src,
                                                  const int* __restrict__ row_ptr,
                                                  const int* __restrict__ counts,
                                                  const float4* __restrict__ el_all,
                                                  int* __restrict__ csr_src,
                                                  float* __restrict__ e0, float* __restrict__ e1,
                                                  float* __restrict__ e2, float* __restrict__ e3,
                                                  int n) {
    int wid = threadIdx.x >> 6, lane = threadIdx.x & 63;
    int nd0 = (blockIdx.x * 4 + wid) * 2;
    if (nd0 >= n) return;
    int g = lane >> 5, lg = lane & 31;
    int ndg = nd0 + g;
    bool valid = ndg < n;
    int d_g = valid ? counts[ndg] : 0;
    int d0 = __shfl(d_g, 0, 64);
    int d1 = __shfl(d_g, 32, 64);
    if (d0 <= 32 && d1 <= 32) {
        int s = valid ? row_ptr[ndg] : 0;
        int eid = 0x7FFFFFFF;
        if (lg < d_g) eid = csr_eid[s + lg];
        int dmax = max(d0, d1);
        int base = lane & 32;
        int rank = 0;
        for (int j = 0; j < dmax; ++j) {
            int ej = __shfl(eid, base + j, 64);
            rank += (ej < eid) ? 1 : 0;
        }
        if (lg < d_g) {
            int sr = e_src[eid];
            float4 ev = el_all[eid];
            csr_src[s + rank] = sr;
            e0[s + rank] = ev.x; e1[s + rank] = ev.y;
            e2[s + rank] = ev.z; e3[s + rank] = ev.w;
        }
        return;
    }
    // slow path: whole wave per node (original 64-lane rank / insertion sort)
    for (int q = 0; q < 2; ++q) {
        int nd = nd0 + q;
        if (nd >= n) continue;
        int s = row_ptr[nd], d = counts[nd];
        if (d == 0) continue;
        if (d <= 64) {
            int eid = 0x7FFFFFFF;
            if (lane < d) eid = csr_eid[s + lane];
            int rank = 0;
            for (int j = 0; j < d; ++j) {
                int ej = __shfl(eid, j, 64);
                rank += (ej < eid) ? 1 : 0;
            }
            if (lane < d) {
                int sr = e_src[eid];
                float4 ev = el_all[eid];
                csr_src[s + rank] = sr;
                e0[s + rank] = ev.x; e1[s + rank] = ev.y;
                e2[s + rank] = ev.z; e3[s + rank] = ev.w;
            }
        } else if (lane == 0) {
            for (int i = 1; i < d; ++i) {
                int key = csr_eid[s + i];
                int j = i - 1;
                while (j >= 0 && csr_eid[s + j] > key) {
                    csr_eid[s + j + 1] = csr_eid[s + j];
                    --j;
                }
                csr_eid[s + j + 1] = key;
            }
            for (int i = 0; i < d; ++i) {
                int eid = csr_eid[s + i];
                float4 ev = el_all[eid];
                csr_src[s + i] = e_src[eid];
                e0[s + i] = ev.x; e1[s + i] = ev.y; e2[s + i] = ev.z; e3[s + i] = ev.w;
            }
        }
    }
}

// ---------------- per-layer: hw = h @ W (register-tiled), ssrc/sdst fused ----------------
__global__ __launch_bounds__(256) void k_gemm(const float* __restrict__ h,
                                              const float* __restrict__ W,
                                              const float* __restrict__ a_s,
                                              const float* __restrict__ a_d,
                                              float* __restrict__ hw,
                                              float* __restrict__ ssrc,
                                              float* __restrict__ sdst, int n) {
    __shared__ float sHT[64 * 68];   // [k][node]
    __shared__ float sW[64 * 64];    // [k][dim]
    int t = threadIdx.x;
    int nbase = blockIdx.x * 64;
    int nrem = n - nbase;
    const float4* W4 = (const float4*)W;
    float4* sW4 = (float4*)sW;
#pragma unroll
    for (int p = 0; p < 4; ++p) sW4[t + p * 256] = W4[t + p * 256];
#pragma unroll
    for (int p = 0; p < 4; ++p) {
        int idx = t + p * 256;            // 0..1023 float4 slots
        int node = idx >> 4, d4 = idx & 15;
        float4 v = make_float4(0.f, 0.f, 0.f, 0.f);
        if (node < nrem) v = ((const float4*)(h + (size_t)(nbase + node) * 64))[d4];
        sHT[(d4 * 4 + 0) * 68 + node] = v.x;
        sHT[(d4 * 4 + 1) * 68 + node] = v.y;
        sHT[(d4 * 4 + 2) * 68 + node] = v.z;
        sHT[(d4 * 4 + 3) * 68 + node] = v.w;
    }
    __syncthreads();
    int nr = (t >> 4) * 4;    // node row base in tile
    int nc = (t & 15) * 4;    // dim col base
    float a0[4], a1[4], a2[4], a3[4];
#pragma unroll
    for (int j = 0; j < 4; ++j) { a0[j] = 0.f; a1[j] = 0.f; a2[j] = 0.f; a3[j] = 0.f; }
    for (int k = 0; k < 64; ++k) {
        float4 hv = *(const float4*)&sHT[k * 68 + nr];
        float4 wv = *(const float4*)&sW[k * 64 + nc];
        a0[0] = fmaf(hv.x, wv.x, a0[0]); a0[1] = fmaf(hv.x, wv.y, a0[1]);
        a0[2] = fmaf(hv.x, wv.z, a0[2]); a0[3] = fmaf(hv.x, wv.w, a0[3]);
        a1[0] = fmaf(hv.y, wv.x, a1[0]); a1[1] = fmaf(hv.y, wv.y, a1[1]);
        a1[2] = fmaf(hv.y, wv.z, a1[2]); a1[3] = fmaf(hv.y, wv.w, a1[3]);
        a2[0] = fmaf(hv.z, wv.x, a2[0]); a2[1] = fmaf(hv.z, wv.y, a2[1]);
        a2[2] = fmaf(hv.z, wv.z, a2[2]); a2[3] = fmaf(hv.z, wv.w, a2[3]);
        a3[0] = fmaf(hv.w, wv.x, a3[0]); a3[1] = fmaf(hv.w, wv.y, a3[1]);
        a3[2] = fmaf(hv.w, wv.z, a3[2]); a3[3] = fmaf(hv.w, wv.w, a3[3]);
    }
    if (nr + 0 < nrem) ((float4*)(hw + (size_t)(nbase + nr + 0) * 64))[t & 15] =
        make_float4(a0[0], a0[1], a0[2], a0[3]);
    if (nr + 1 < nrem) ((float4*)(hw + (size_t)(nbase + nr + 1) * 64))[t & 15] =
        make_float4(a1[0], a1[1], a1[2], a1[3]);
    if (nr + 2 < nrem) ((float4*)(hw + (size_t)(nbase + nr + 2) * 64))[t & 15] =
        make_float4(a2[0], a2[1], a2[2], a2[3]);
    if (nr + 3 < nrem) ((float4*)(hw + (size_t)(nbase + nr + 3) * 64))[t & 15] =
        make_float4(a3[0], a3[1], a3[2], a3[3]);
    float as0 = a_s[nc], as1 = a_s[nc + 1], as2 = a_s[nc + 2], as3 = a_s[nc + 3];
    float ad0 = a_d[nc], ad1 = a_d[nc + 1], ad2 = a_d[nc + 2], ad3 = a_d[nc + 3];
    float ts0 = fmaf(a0[3], as3, fmaf(a0[2], as2, fmaf(a0[1], as1, a0[0] * as0)));
    float ts1 = fmaf(a1[3], as3, fmaf(a1[2], as2, fmaf(a1[1], as1, a1[0] * as0)));
    float ts2 = fmaf(a2[3], as3, fmaf(a2[2], as2, fmaf(a2[1], as1, a2[0] * as0)));
    float ts3 = fmaf(a3[3], as3, fmaf(a3[2], as2, fmaf(a3[1], as1, a3[0] * as0)));
    float td0 = fmaf(a0[3], ad3, fmaf(a0[2], ad2, fmaf(a0[1], ad1, a0[0] * ad0)));
    float td1 = fmaf(a1[3], ad3, fmaf(a1[2], ad2, fmaf(a1[1], ad1, a1[0] * ad0)));
    float td2 = fmaf(a2[3], ad3, fmaf(a2[2], ad2, fmaf(a2[1], ad1, a2[0] * ad0)));
    float td3 = fmaf(a3[3], ad3, fmaf(a3[2], ad2, fmaf(a3[1], ad1, a3[0] * ad0)));
#pragma unroll
    for (int off = 1; off < 16; off <<= 1) {
        ts0 += __shfl_xor(ts0, off, 64); ts1 += __shfl_xor(ts1, off, 64);
        ts2 += __shfl_xor(ts2, off, 64); ts3 += __shfl_xor(ts3, off, 64);
        td0 += __shfl_xor(td0, off, 64); td1 += __shfl_xor(td1, off, 64);
        td2 += __shfl_xor(td2, off, 64); td3 += __shfl_xor(td3, off, 64);
    }
    if ((t & 15) == 0) {
        if (nr + 0 < nrem) { ssrc[nbase + nr + 0] = ts0; sdst[nbase + nr + 0] = td0; }
        if (nr + 1 < nrem) { ssrc[nbase + nr + 1] = ts1; sdst[nbase + nr + 1] = td1; }
        if (nr + 2 < nrem) { ssrc[nbase + nr + 2] = ts2; sdst[nbase + nr + 2] = td2; }
        if (nr + 3 < nrem) { ssrc[nbase + nr + 3] = ts3; sdst[nbase + nr + 3] = td3; }
    }
}

// whole-wave (64-lane) single-node path (bit-exact reference path)
__device__ __forceinline__ void row_one_64(int nd, int lane,
                                           const float* __restrict__ hw,
                                           const float* __restrict__ ssrc,
                                           const float* __restrict__ sdstA,
                                           const int* __restrict__ csr_src,
                                           const float* __restrict__ elpL,
                                           const int* __restrict__ row_ptr,
                                           const int* __restrict__ counts,
                                           const float* __restrict__ bias,
                                           int relu_flag, float* __restrict__ hout) {
    int start = row_ptr[nd], deg = counts[nd];
    if (deg == 0) {
        float outv = bias[lane];
        if (relu_flag) outv = fmaxf(outv, 0.f);
        hout[(size_t)nd * 64 + lane] = outv;
        return;
    }
    if (deg <= 64) {
        float sdn = sdstA[nd];
        int p = start + lane;
        int s_l = 0;
        float sc = -INFINITY;
        if (lane < deg) {
            s_l = csr_src[p];
            sc = ssrc[s_l] + sdn + elpL[p];
            sc = sc > 0.f ? sc : 0.2f * sc;
        }
        float mx = sc;
#pragma unroll
        for (int off = 32; off; off >>= 1) mx = fmaxf(mx, __shfl_xor(mx, off, 64));
        float pe = (lane < deg) ? __expf(sc - mx) : 0.f;
        float dsum = pe;
#pragma unroll
        for (int off = 32; off; off >>= 1) dsum += __shfl_xor(dsum, off, 64);
        const float* hwL = hw + lane;
        float acc = 0.f;
        int t0 = __shfl(s_l, 0, 64), t1 = __shfl(s_l, 1, 64);
        int t2 = __shfl(s_l, 2, 64), t3 = __shfl(s_l, 3, 64);
        int t4 = __shfl(s_l, 4, 64), t5 = __shfl(s_l, 5, 64);
        int t6 = __shfl(s_l, 6, 64), t7 = __shfl(s_l, 7, 64);
        float v0 = hwL[(size_t)t0 * 64], v1 = hwL[(size_t)t1 * 64];
        float v2 = hwL[(size_t)t2 * 64], v3 = hwL[(size_t)t3 * 64];
        float v4 = hwL[(size_t)t4 * 64], v5 = hwL[(size_t)t5 * 64];
        float v6 = hwL[(size_t)t6 * 64], v7 = hwL[(size_t)t7 * 64];
        for (int i = 0; i < deg; i += 8) {
            float p0 = __shfl(pe, i, 64),     p1 = __shfl(pe, i + 1, 64);
            float p2 = __shfl(pe, i + 2, 64), p3 = __shfl(pe, i + 3, 64);
            float p4 = __shfl(pe, i + 4, 64), p5 = __shfl(pe, i + 5, 64);
            float p6 = __shfl(pe, i + 6, 64), p7 = __shfl(pe, i + 7, 64);
            int u0 = __shfl(s_l, (i + 8) & 63, 64),  u1 = __shfl(s_l, (i + 9) & 63, 64);
            int u2 = __shfl(s_l, (i + 10) & 63, 64), u3 = __shfl(s_l, (i + 11) & 63, 64);
            int u4 = __shfl(s_l, (i + 12) & 63, 64), u5 = __shfl(s_l, (i + 13) & 63, 64);
            int u6 = __shfl(s_l, (i + 14) & 63, 64), u7 = __shfl(s_l, (i + 15) & 63, 64);
            float w0 = v0, w1 = v1, w2 = v2, w3 = v3,
                  w4 = v4, w5 = v5, w6 = v6, w7 = v7;
            v0 = hwL[(size_t)u0 * 64]; v1 = hwL[(size_t)u1 * 64];
            v2 = hwL[(size_t)u2 * 64]; v3 = hwL[(size_t)u3 * 64];
            v4 = hwL[(size_t)u4 * 64]; v5 = hwL[(size_t)u5 * 64];
            v6 = hwL[(size_t)u6 * 64]; v7 = hwL[(size_t)u7 * 64];
            acc = fmaf(p0, w0, acc);
            acc = fmaf(p1, w1, acc);
            acc = fmaf(p2, w2, acc);
            acc = fmaf(p3, w3, acc);
            acc = fmaf(p4, w4, acc);
            acc = fmaf(p5, w5, acc);
            acc = fmaf(p6, w6, acc);
            acc = fmaf(p7, w7, acc);
        }
        float outv = acc / dsum + bias[lane];
        if (relu_flag) outv = fmaxf(outv, 0.f);
        hout[(size_t)nd * 64 + lane] = outv;
        return;
    }
    // fallback deg>64 (never expected; correctness only)
    {
        float sdn = sdstA[nd];
        float mx = -INFINITY;
        for (int i = lane; i < deg; i += 64) {
            int p = start + i;
            float sc = ssrc[csr_src[p]] + sdn + elpL[p];
            sc = sc > 0.f ? sc : 0.2f * sc;
            mx = fmaxf(mx, sc);
        }
#pragma unroll
        for (int off = 32; off; off >>= 1) mx = fmaxf(mx, __shfl_xor(mx, off, 64));
        float dsum = 0.f;
        for (int i = lane; i < deg; i += 64) {
            int p = start + i;
            float sc = ssrc[csr_src[p]] + sdn + elpL[p];
            sc = sc > 0.f ? sc : 0.2f * sc;
            dsum += __expf(sc - mx);
        }
#pragma unroll
        for (int off = 32; off; off >>= 1) dsum += __shfl_xor(dsum, off, 64);
        float acc = 0.f;
        for (int i = 0; i < deg; ++i) {
            int p = start + i;
            int s = csr_src[p];
            float sc = ssrc[s] + sdn + elpL[p];
            sc = sc > 0.f ? sc : 0.2f * sc;
            float pex = __expf(sc - mx);
            acc = fmaf(pex, hw[(size_t)s * 64 + lane], acc);
        }
        float outv = acc / dsum + bias[lane];
        if (relu_flag) outv = fmaxf(outv, 0.f);
        hout[(size_t)nd * 64 + lane] = outv;
    }
}

// ---------------- per-layer: softmax + aggregate, 2 nodes per wave ----------------
// Fast path (both degs in [1,32]): two 32-lane groups, lane owns dims
// (2lg, 2lg+1) as float2; 16-deep software-pipelined gathers. fma chain
// remains strictly ascending-edge-order (pe=0 padding exact) -> bit-exact.
__global__ __launch_bounds__(256) void k_row(const float* __restrict__ hw,
                                             const float* __restrict__ ssrc,
                                             const float* __restrict__ sdstA,
                                             const int* __restrict__ csr_src,
                                             const float* __restrict__ elpL,
                                             const int* __restrict__ row_ptr,
                                             const int* __restrict__ counts,
                                             const float* __restrict__ bias,
                                             int relu_flag, float* __restrict__ hout, int n) {
    int wid = threadIdx.x >> 6, lane = threadIdx.x & 63;
    int nd0 = (blockIdx.x * 4 + wid) * 2;
    if (nd0 >= n) return;
    int g = lane >> 5, lg = lane & 31;
    int ndg = nd0 + g;
    bool v1ok = (nd0 + 1) < n;
    int deg_g = (ndg < n) ? counts[ndg] : 0;
    int deg0 = __shfl(deg_g, 0, 64);
    int deg1 = __shfl(deg_g, 32, 64);
    bool fast = v1ok && deg0 >= 1 && deg0 <= 32 && deg1 >= 1 && deg1 <= 32;
    if (fast) {
        int start = row_ptr[ndg];
        float sdn = sdstA[ndg];
        int p = start + lg;
        int s_l = 0;
        float sc = -INFINITY;
        if (lg < deg_g) {
            s_l = csr_src[p];
            sc = ssrc[s_l] + sdn + elpL[p];
            sc = sc > 0.f ? sc : 0.2f * sc;
        }
        float mx = sc;
#pragma unroll
        for (int off = 16; off; off >>= 1) mx = fmaxf(mx, __shfl_xor(mx, off, 64));
        float pe = (lg < deg_g) ? __expf(sc - mx) : 0.f;
        float dsum = pe;
#pragma unroll
        for (int off = 16; off; off >>= 1) dsum += __shfl_xor(dsum, off, 64);
        int degmax = max(deg0, deg1);
        int base = lane & 32;          // group's lane base for broadcasts
        const float2* hw2 = (const float2*)hw;
        float2 acc = make_float2(0.f, 0.f);
        float2 v[16];
#pragma unroll
        for (int k = 0; k < 16; ++k) {
            int tk = __shfl(s_l, base + k, 64);
            v[k] = hw2[(size_t)tk * 32 + lg];
        }
        for (int i = 0; i < degmax; i += 16) {
            float pk[16];
#pragma unroll
            for (int k = 0; k < 16; ++k) pk[k] = __shfl(pe, base + ((i + k) & 31), 64);
            float2 w[16];
#pragma unroll
            for (int k = 0; k < 16; ++k) w[k] = v[k];
#pragma unroll
            for (int k = 0; k < 16; ++k) {
                int uk = __shfl(s_l, base + ((i + 16 + k) & 31), 64);
                v[k] = hw2[(size_t)uk * 32 + lg];
            }
#pragma unroll
            for (int k = 0; k < 16; ++k) {
                acc.x = fmaf(pk[k], w[k].x, acc.x);
                acc.y = fmaf(pk[k], w[k].y, acc.y);
            }
        }
        float2 bv = ((const float2*)bias)[lg];
        float2 o;
        o.x = acc.x / dsum + bv.x;
        o.y = acc.y / dsum + bv.y;
        if (relu_flag) { o.x = fmaxf(o.x, 0.f); o.y = fmaxf(o.y, 0.f); }
        ((float2*)(hout + (size_t)ndg * 64))[lg] = o;
        return;
    }
    // slow path: whole wave processes each node sequentially (bit-exact)
    for (int q = 0; q < 2; ++q) {
        int nd = nd0 + q;
        if (nd < n)
            row_one_64(nd, lane, hw, ssrc, sdstA, csr_src, elpL, row_ptr, counts,
                       bias, relu_flag, hout);
    }
}

// ---------------- pooling phase A: per-(subchunk, graph) partial sums ----------------
__global__ __launch_bounds__(256) void k_pool_part(const float* __restrict__ h,
                                                   const int* __restrict__ batch,
                                                   float* __restrict__ partial, int n) {
    int g = blockIdx.y, j = blockIdx.x;
    int lo = 0, hi = n;
    while (lo < hi) { int mid = (lo + hi) >> 1; if (batch[mid] < g) lo = mid + 1; else hi = mid; }
    int start = lo;
    lo = start; hi = n;
    while (lo < hi) { int mid = (lo + hi) >> 1; if (batch[mid] < g + 1) lo = mid + 1; else hi = mid; }
    int end = lo;
    int cnt = end - start;
    int chunk = (cnt + PJ - 1) / PJ;
    int clo = start + j * chunk;
    int chi = min(clo + chunk, end);
    int lane = threadIdx.x & 63, q = threadIdx.x >> 6;
    float acc = 0.f;
    for (int nd = clo + q; nd < chi; nd += 4) acc += h[(size_t)nd * 64 + lane];
    __shared__ float s[4][64];
    s[q][lane] = acc;
    __syncthreads();
    if (threadIdx.x < 64) {
        float tot = s[0][threadIdx.x] + s[1][threadIdx.x] + s[2][threadIdx.x] + s[3][threadIdx.x];
        partial[((size_t)g * PJ + j) * 64 + threadIdx.x] = tot;
    }
}

// ---------------- FC with fused pooling phase B ----------------
__global__ __launch_bounds__(256) void k_fc(const float* __restrict__ partial,
                                            const int* __restrict__ batch,
                                            const float* __restrict__ Wfc,
                                            const float* __restrict__ bfc,
                                            float* __restrict__ out, int n) {
    int g = blockIdx.y;
    int c = blockIdx.x * 256 + threadIdx.x;
    __shared__ float sp[64];
    if (threadIdx.x < 64) {
        int d = threadIdx.x;
        float tot = 0.f;
#pragma unroll
        for (int j = 0; j < PJ; ++j) tot += partial[((size_t)g * PJ + j) * 64 + d];
        int lo = 0, hi = n;
        while (lo < hi) { int mid = (lo + hi) >> 1; if (batch[mid] < g) lo = mid + 1; else hi = mid; }
        int start = lo;
        lo = start; hi = n;
        while (lo < hi) { int mid = (lo + hi) >> 1; if (batch[mid] < g + 1) lo = mid + 1; else hi = mid; }
        int cnt = lo - start;
        sp[d] = tot / fmaxf((float)cnt, 1.0f);
    }
    __syncthreads();
    float acc = bfc[c];
#pragma unroll
    for (int k = 0; k < 64; ++k) acc = fmaf(sp[k], Wfc[k * 2048 + c], acc);
    out[(size_t)g * 2048 + c] = acc;
}

extern "C" void kernel_launch(void* const* d_in, const int* in_sizes, int n_in,
                              void* d_out, int out_size, void* d_ws, size_t ws_size,
                              hipStream_t stream) {
    const float* x = (const float*)d_in[0];
    const int* edge_index = (const int*)d_in[1];
    const float* edge_attr = (const float*)d_in[2];
    const int* batch = (const int*)d_in[3];
    const float* W = (const float*)d_in[4];
    const float* a_src = (const float*)d_in[5];
    const float* a_dst = (const float*)d_in[6];
    const float* We = (const float*)d_in[7];
    const float* a_e = (const float*)d_in[8];
    const float* b = (const float*)d_in[9];
    const float* Wfc = (const float*)d_in[10];
    const float* bfc = (const float*)d_in[11];
    float* out = (float*)d_out;

    char* ws = (char*)d_ws;
    size_t off = 0;
    auto alloc = [&](size_t bytes) {
        void* p = ws + off;
        off = (off + bytes + 255) & ~(size_t)255;
        return p;
    };
    float* h0      = (float*)alloc((size_t)NN * 64 * 4);
    float* h1      = (float*)alloc((size_t)NN * 64 * 4);
    float* hw      = (float*)alloc((size_t)NN * 64 * 4);
    float* ssrc    = (float*)alloc((size_t)NN * 4);
    float* sdst    = (float*)alloc((size_t)NN * 4);
    float* el_all  = (float*)alloc((size_t)EE * 16);
    float* elpT    = (float*)alloc((size_t)EE * 4 * 4);   // 4 per-layer scalar planes
    int*   csr_src = (int*)alloc((size_t)EE * 4);
    int*   csr_eid = (int*)alloc((size_t)EE * 4);
    int*   counts  = (int*)alloc((size_t)NN * 4);
    int*   row_ptr = (int*)alloc((size_t)NN * 4);
    int*   cursor  = (int*)alloc((size_t)NN * 4);
    int*   bsum    = (int*)alloc(256 * 4);
    float* partial = (float*)alloc((size_t)GG * PJ * 64 * 4);
    (void)ws_size; (void)in_sizes; (void)n_in; (void)out_size;

    const int* e_src = edge_index;
    const int* e_dst = edge_index + EE;
    const int EB = EE / 256;            // 3125
    const int NB = (NN + 255) / 256;    // 196

    hipMemsetAsync(counts, 0, (size_t)NN * 4, stream);
    hipMemsetAsync(cursor, 0, (size_t)NN * 4, stream);

    k_el<<<EB, 256, 0, stream>>>(edge_attr, We, a_e, el_all, EE);
    k_hist<<<dim3(NXCD, EB), 256, 0, stream>>>(e_dst, counts, EE);
    k_scan1<<<NB, 256, 0, stream>>>(counts, bsum, NN);
    k_scan2<<<1, 256, 0, stream>>>(bsum, NB);
    k_scan3<<<NB, 256, 0, stream>>>(counts, bsum, row_ptr, NN);
    k_fill<<<dim3(NXCD, EB), 256, 0, stream>>>(e_dst, row_ptr, cursor, csr_eid, EE);
    k_sortperm<<<(NN + 7) / 8, 256, 0, stream>>>(csr_eid, e_src, row_ptr, counts,
                                                 (const float4*)el_all, csr_src,
                                                 elpT, elpT + EE, elpT + 2 * (size_t)EE,
                                                 elpT + 3 * (size_t)EE, NN);

    const float* hin = x;
    float* hbufs[2] = {h0, h1};
    for (int l = 0; l < LL; ++l) {
        k_gemm<<<(NN + 63) / 64, 256, 0, stream>>>(hin, W + l * 4096, a_src + l * 64,
                                                   a_dst + l * 64, hw, ssrc, sdst, NN);
        float* hout = hbufs[l & 1];
        k_row<<<(NN + 7) / 8, 256, 0, stream>>>(hw, ssrc, sdst, csr_src,
                                                elpT + (size_t)l * EE, row_ptr, counts,
                                                b + l * 64, (l < LL - 1) ? 1 : 0, hout, NN);
        hin = hout;
    }
    k_pool_part<<<dim3(PJ, GG), 256, 0, stream>>>(hin, batch, partial, NN);
    k_fc<<<dim3(2048 / 256, GG), 256, 0, stream>>>(partial, batch, Wfc, bfc, out, NN);
}

// Round 12
// 337.134 us; speedup vs baseline: 1.0257x; 1.0257x over previous
//
#include <hip/hip_runtime.h>
#include <hip/hip_bf16.h>

#define NN 50000
#define EE 800000
#define DD 64
#define LL 4
#define GG 64
#define PJ 16   // pooling sub-blocks per graph
#define NXCD 8
#define DRANGE (NN / NXCD)   // 6250 dst nodes per XCD range

// pure stream: el_all[e] = float4 of (edge_attr[e] . ce[l]) for l=0..3.
// ce recomputed per block (bit-identical sequential loop; proven in R6).
__global__ __launch_bounds__(256) void k_el(const float* __restrict__ ea,
                                            const float* __restrict__ We,
                                            const float* __restrict__ a_e,
                                            float* __restrict__ el_all, int ne) {
    __shared__ float sce[64];
    if (threadIdx.x < 64) {
        int l = threadIdx.x >> 4, k = threadIdx.x & 15;
        float acc = 0.f;
        for (int j = 0; j < 64; ++j)
            acc += We[l * 1024 + k * 64 + j] * a_e[l * 64 + j];
        sce[threadIdx.x] = acc;
    }
    __syncthreads();
    int e = blockIdx.x * 256 + threadIdx.x;
    if (e >= ne) return;
    const float4* p4 = reinterpret_cast<const float4*>(ea + (size_t)e * 16);
    float v[16];
    float4 q;
    q = p4[0]; v[0] = q.x; v[1] = q.y; v[2] = q.z; v[3] = q.w;
    q = p4[1]; v[4] = q.x; v[5] = q.y; v[6] = q.z; v[7] = q.w;
    q = p4[2]; v[8] = q.x; v[9] = q.y; v[10] = q.z; v[11] = q.w;
    q = p4[3]; v[12] = q.x; v[13] = q.y; v[14] = q.z; v[15] = q.w;
    float o[4];
#pragma unroll
    for (int l = 0; l < 4; ++l) {
        float a = 0.f;
#pragma unroll
        for (int k = 0; k < 16; ++k) a = fmaf(v[k], sce[l * 16 + k], a);
        o[l] = a;
    }
    reinterpret_cast<float4*>(el_all)[e] = make_float4(o[0], o[1], o[2], o[3]);
}

// XCD-range-partitioned histogram
__global__ __launch_bounds__(256) void k_hist(const int* __restrict__ dst,
                                              int* __restrict__ counts, int ne) {
    int r = blockIdx.x;
    int e = blockIdx.y * 256 + threadIdx.x;
    if (e >= ne) return;
    int d = dst[e];
    int rlo = r * DRANGE;
    if (d < rlo || d >= rlo + DRANGE) return;
    atomicAdd(&counts[d], 1);
}

// ---------------- CSR build ----------------
__global__ void k_scan1(const int* __restrict__ counts, int* __restrict__ bsum, int n) {
    __shared__ int s[256];
    int i = blockIdx.x * 256 + threadIdx.x;
    s[threadIdx.x] = (i < n) ? counts[i] : 0;
    __syncthreads();
    for (int off = 128; off; off >>= 1) {
        if (threadIdx.x < off) s[threadIdx.x] += s[threadIdx.x + off];
        __syncthreads();
    }
    if (threadIdx.x == 0) bsum[blockIdx.x] = s[0];
}

__global__ void k_scan2(int* __restrict__ bsum, int nb) {  // one block, nb<=256
    __shared__ int s[256];
    int t = threadIdx.x;
    int v = (t < nb) ? bsum[t] : 0;
    s[t] = v;
    __syncthreads();
    for (int off = 1; off < 256; off <<= 1) {
        int x = (t >= off) ? s[t - off] : 0;
        __syncthreads();
        s[t] += x;
        __syncthreads();
    }
    if (t < nb) bsum[t] = s[t] - v;  // exclusive
}

__global__ void k_scan3(const int* __restrict__ counts, const int* __restrict__ bsum,
                        int* __restrict__ row_ptr, int n) {
    __shared__ int s[256];
    int t = threadIdx.x;
    int i = blockIdx.x * 256 + t;
    int v = (i < n) ? counts[i] : 0;
    s[t] = v;
    __syncthreads();
    for (int off = 1; off < 256; off <<= 1) {
        int x = (t >= off) ? s[t - off] : 0;
        __syncthreads();
        s[t] += x;
        __syncthreads();
    }
    if (i < n) row_ptr[i] = s[t] - v + bsum[blockIdx.x];
}

// XCD-range-partitioned scatter
__global__ __launch_bounds__(256) void k_fill(const int* __restrict__ dst,
                                              const int* __restrict__ row_ptr,
                                              int* __restrict__ cursor,
                                              int* __restrict__ csr_eid, int ne) {
    int r = blockIdx.x;
    int e = blockIdx.y * 256 + threadIdx.x;
    if (e >= ne) return;
    int d = dst[e];
    int rlo = r * DRANGE;
    if (d < rlo || d >= rlo + DRANGE) return;
    int pos = row_ptr[d] + atomicAdd(&cursor[d], 1);
    csr_eid[pos] = e;
}

// deterministic row order (sort by eid) via rank computation.
// Fast path: 2 nodes per wave (two 32-lane groups), uniform-length rank loop
// with MAX-sentinel padding (identical ranks as the 64-lane version).
__global__ __launch_bounds__(256) void k_sortperm(int* __restrict__ csr_eid,
                                                  const int* __restrict__ e_src,
                                                  const int* __restrict__ row_ptr,
                                                  const int* __restrict__ counts,
                                                  const float4* __restrict__ el_all,
                                                  int* __restrict__ csr_src,
                                                  float* __restrict__ e0, float* __restrict__ e1,
                                                  float* __restrict__ e2, float* __restrict__ e3,
                                                  int n) {
    int wid = threadIdx.x >> 6, lane = threadIdx.x & 63;
    int nd0 = (blockIdx.x * 4 + wid) * 2;
    if (nd0 >= n) return;
    int g = lane >> 5, lg = lane & 31;
    int ndg = nd0 + g;
    bool valid = ndg < n;
    int d_g = valid ? counts[ndg] : 0;
    int d0 = __shfl(d_g, 0, 64);
    int d1 = __shfl(d_g, 32, 64);
    if (d0 <= 32 && d1 <= 32) {
        int s = valid ? row_ptr[ndg] : 0;
        int eid = 0x7FFFFFFF;
        if (lg < d_g) eid = csr_eid[s + lg];
        int dmax = max(d0, d1);
        int base = lane & 32;
        int rank = 0;
        for (int j = 0; j < dmax; ++j) {
            int ej = __shfl(eid, base + j, 64);
            rank += (ej < eid) ? 1 : 0;
        }
        if (lg < d_g) {
            int sr = e_src[eid];
            float4 ev = el_all[eid];
            csr_src[s + rank] = sr;
            e0[s + rank] = ev.x; e1[s + rank] = ev.y;
            e2[s + rank] = ev.z; e3[s + rank] = ev.w;
        }
        return;
    }
    // slow path: whole wave per node (original 64-lane rank / insertion sort)
    for (int q = 0; q < 2; ++q) {
        int nd = nd0 + q;
        if (nd >= n) continue;
        int s = row_ptr[nd], d = counts[nd];
        if (d == 0) continue;
        if (d <= 64) {
            int eid = 0x7FFFFFFF;
            if (lane < d) eid = csr_eid[s + lane];
            int rank = 0;
            for (int j = 0; j < d; ++j) {
                int ej = __shfl(eid, j, 64);
                rank += (ej < eid) ? 1 : 0;
            }
            if (lane < d) {
                int sr = e_src[eid];
                float4 ev = el_all[eid];
                csr_src[s + rank] = sr;
                e0[s + rank] = ev.x; e1[s + rank] = ev.y;
                e2[s + rank] = ev.z; e3[s + rank] = ev.w;
            }
        } else if (lane == 0) {
            for (int i = 1; i < d; ++i) {
                int key = csr_eid[s + i];
                int j = i - 1;
                while (j >= 0 && csr_eid[s + j] > key) {
                    csr_eid[s + j + 1] = csr_eid[s + j];
                    --j;
                }
                csr_eid[s + j + 1] = key;
            }
            for (int i = 0; i < d; ++i) {
                int eid = csr_eid[s + i];
                float4 ev = el_all[eid];
                csr_src[s + i] = e_src[eid];
                e0[s + i] = ev.x; e1[s + i] = ev.y; e2[s + i] = ev.z; e3[s + i] = ev.w;
            }
        }
    }
}

// ---------------- per-layer: hw = h @ W (register-tiled), ssrc/sdst fused ----------------
__global__ __launch_bounds__(256) void k_gemm(const float* __restrict__ h,
                                              const float* __restrict__ W,
                                              const float* __restrict__ a_s,
                                              const float* __restrict__ a_d,
                                              float* __restrict__ hw,
                                              float* __restrict__ ssrc,
                                              float* __restrict__ sdst, int n) {
    __shared__ float sHT[64 * 68];   // [k][node]
    __shared__ float sW[64 * 64];    // [k][dim]
    int t = threadIdx.x;
    int nbase = blockIdx.x * 64;
    int nrem = n - nbase;
    const float4* W4 = (const float4*)W;
    float4* sW4 = (float4*)sW;
#pragma unroll
    for (int p = 0; p < 4; ++p) sW4[t + p * 256] = W4[t + p * 256];
#pragma unroll
    for (int p = 0; p < 4; ++p) {
        int idx = t + p * 256;            // 0..1023 float4 slots
        int node = idx >> 4, d4 = idx & 15;
        float4 v = make_float4(0.f, 0.f, 0.f, 0.f);
        if (node < nrem) v = ((const float4*)(h + (size_t)(nbase + node) * 64))[d4];
        sHT[(d4 * 4 + 0) * 68 + node] = v.x;
        sHT[(d4 * 4 + 1) * 68 + node] = v.y;
        sHT[(d4 * 4 + 2) * 68 + node] = v.z;
        sHT[(d4 * 4 + 3) * 68 + node] = v.w;
    }
    __syncthreads();
    int nr = (t >> 4) * 4;    // node row base in tile
    int nc = (t & 15) * 4;    // dim col base
    float a0[4], a1[4], a2[4], a3[4];
#pragma unroll
    for (int j = 0; j < 4; ++j) { a0[j] = 0.f; a1[j] = 0.f; a2[j] = 0.f; a3[j] = 0.f; }
    for (int k = 0; k < 64; ++k) {
        float4 hv = *(const float4*)&sHT[k * 68 + nr];
        float4 wv = *(const float4*)&sW[k * 64 + nc];
        a0[0] = fmaf(hv.x, wv.x, a0[0]); a0[1] = fmaf(hv.x, wv.y, a0[1]);
        a0[2] = fmaf(hv.x, wv.z, a0[2]); a0[3] = fmaf(hv.x, wv.w, a0[3]);
        a1[0] = fmaf(hv.y, wv.x, a1[0]); a1[1] = fmaf(hv.y, wv.y, a1[1]);
        a1[2] = fmaf(hv.y, wv.z, a1[2]); a1[3] = fmaf(hv.y, wv.w, a1[3]);
        a2[0] = fmaf(hv.z, wv.x, a2[0]); a2[1] = fmaf(hv.z, wv.y, a2[1]);
        a2[2] = fmaf(hv.z, wv.z, a2[2]); a2[3] = fmaf(hv.z, wv.w, a2[3]);
        a3[0] = fmaf(hv.w, wv.x, a3[0]); a3[1] = fmaf(hv.w, wv.y, a3[1]);
        a3[2] = fmaf(hv.w, wv.z, a3[2]); a3[3] = fmaf(hv.w, wv.w, a3[3]);
    }
    if (nr + 0 < nrem) ((float4*)(hw + (size_t)(nbase + nr + 0) * 64))[t & 15] =
        make_float4(a0[0], a0[1], a0[2], a0[3]);
    if (nr + 1 < nrem) ((float4*)(hw + (size_t)(nbase + nr + 1) * 64))[t & 15] =
        make_float4(a1[0], a1[1], a1[2], a1[3]);
    if (nr + 2 < nrem) ((float4*)(hw + (size_t)(nbase + nr + 2) * 64))[t & 15] =
        make_float4(a2[0], a2[1], a2[2], a2[3]);
    if (nr + 3 < nrem) ((float4*)(hw + (size_t)(nbase + nr + 3) * 64))[t & 15] =
        make_float4(a3[0], a3[1], a3[2], a3[3]);
    float as0 = a_s[nc], as1 = a_s[nc + 1], as2 = a_s[nc + 2], as3 = a_s[nc + 3];
    float ad0 = a_d[nc], ad1 = a_d[nc + 1], ad2 = a_d[nc + 2], ad3 = a_d[nc + 3];
    float ts0 = fmaf(a0[3], as3, fmaf(a0[2], as2, fmaf(a0[1], as1, a0[0] * as0)));
    float ts1 = fmaf(a1[3], as3, fmaf(a1[2], as2, fmaf(a1[1], as1, a1[0] * as0)));
    float ts2 = fmaf(a2[3], as3, fmaf(a2[2], as2, fmaf(a2[1], as1, a2[0] * as0)));
    float ts3 = fmaf(a3[3], as3, fmaf(a3[2], as2, fmaf(a3[1], as1, a3[0] * as0)));
    float td0 = fmaf(a0[3], ad3, fmaf(a0[2], ad2, fmaf(a0[1], ad1, a0[0] * ad0)));
    float td1 = fmaf(a1[3], ad3, fmaf(a1[2], ad2, fmaf(a1[1], ad1, a1[0] * ad0)));
    float td2 = fmaf(a2[3], ad3, fmaf(a2[2], ad2, fmaf(a2[1], ad1, a2[0] * ad0)));
    float td3 = fmaf(a3[3], ad3, fmaf(a3[2], ad2, fmaf(a3[1], ad1, a3[0] * ad0)));
#pragma unroll
    for (int off = 1; off < 16; off <<= 1) {
        ts0 += __shfl_xor(ts0, off, 64); ts1 += __shfl_xor(ts1, off, 64);
        ts2 += __shfl_xor(ts2, off, 64); ts3 += __shfl_xor(ts3, off, 64);
        td0 += __shfl_xor(td0, off, 64); td1 += __shfl_xor(td1, off, 64);
        td2 += __shfl_xor(td2, off, 64); td3 += __shfl_xor(td3, off, 64);
    }
    if ((t & 15) == 0) {
        if (nr + 0 < nrem) { ssrc[nbase + nr + 0] = ts0; sdst[nbase + nr + 0] = td0; }
        if (nr + 1 < nrem) { ssrc[nbase + nr + 1] = ts1; sdst[nbase + nr + 1] = td1; }
        if (nr + 2 < nrem) { ssrc[nbase + nr + 2] = ts2; sdst[nbase + nr + 2] = td2; }
        if (nr + 3 < nrem) { ssrc[nbase + nr + 3] = ts3; sdst[nbase + nr + 3] = td3; }
    }
}

// whole-wave (64-lane) single-node path (bit-exact reference path)
__device__ __forceinline__ void row_one_64(int nd, int lane,
                                           const float* __restrict__ hw,
                                           const float* __restrict__ ssrc,
                                           const float* __restrict__ sdstA,
                                           const int* __restrict__ csr_src,
                                           const float* __restrict__ elpL,
                                           const int* __restrict__ row_ptr,
                                           const int* __restrict__ counts,
                                           const float* __restrict__ bias,
                                           int relu_flag, float* __restrict__ hout) {
    int start = row_ptr[nd], deg = counts[nd];
    if (deg == 0) {
        float outv = bias[lane];
        if (relu_flag) outv = fmaxf(outv, 0.f);
        hout[(size_t)nd * 64 + lane] = outv;
        return;
    }
    if (deg <= 64) {
        float sdn = sdstA[nd];
        int p = start + lane;
        int s_l = 0;
        float sc = -INFINITY;
        if (lane < deg) {
            s_l = csr_src[p];
            sc = ssrc[s_l] + sdn + elpL[p];
            sc = sc > 0.f ? sc : 0.2f * sc;
        }
        float mx = sc;
#pragma unroll
        for (int off = 32; off; off >>= 1) mx = fmaxf(mx, __shfl_xor(mx, off, 64));
        float pe = (lane < deg) ? __expf(sc - mx) : 0.f;
        float dsum = pe;
#pragma unroll
        for (int off = 32; off; off >>= 1) dsum += __shfl_xor(dsum, off, 64);
        const float* hwL = hw + lane;
        float acc = 0.f;
        int t0 = __shfl(s_l, 0, 64), t1 = __shfl(s_l, 1, 64);
        int t2 = __shfl(s_l, 2, 64), t3 = __shfl(s_l, 3, 64);
        int t4 = __shfl(s_l, 4, 64), t5 = __shfl(s_l, 5, 64);
        int t6 = __shfl(s_l, 6, 64), t7 = __shfl(s_l, 7, 64);
        float v0 = hwL[(size_t)t0 * 64], v1 = hwL[(size_t)t1 * 64];
        float v2 = hwL[(size_t)t2 * 64], v3 = hwL[(size_t)t3 * 64];
        float v4 = hwL[(size_t)t4 * 64], v5 = hwL[(size_t)t5 * 64];
        float v6 = hwL[(size_t)t6 * 64], v7 = hwL[(size_t)t7 * 64];
        for (int i = 0; i < deg; i += 8) {
            float p0 = __shfl(pe, i, 64),     p1 = __shfl(pe, i + 1, 64);
            float p2 = __shfl(pe, i + 2, 64), p3 = __shfl(pe, i + 3, 64);
            float p4 = __shfl(pe, i + 4, 64), p5 = __shfl(pe, i + 5, 64);
            float p6 = __shfl(pe, i + 6, 64), p7 = __shfl(pe, i + 7, 64);
            int u0 = __shfl(s_l, (i + 8) & 63, 64),  u1 = __shfl(s_l, (i + 9) & 63, 64);
            int u2 = __shfl(s_l, (i + 10) & 63, 64), u3 = __shfl(s_l, (i + 11) & 63, 64);
            int u4 = __shfl(s_l, (i + 12) & 63, 64), u5 = __shfl(s_l, (i + 13) & 63, 64);
            int u6 = __shfl(s_l, (i + 14) & 63, 64), u7 = __shfl(s_l, (i + 15) & 63, 64);
            float w0 = v0, w1 = v1, w2 = v2, w3 = v3,
                  w4 = v4, w5 = v5, w6 = v6, w7 = v7;
            v0 = hwL[(size_t)u0 * 64]; v1 = hwL[(size_t)u1 * 64];
            v2 = hwL[(size_t)u2 * 64]; v3 = hwL[(size_t)u3 * 64];
            v4 = hwL[(size_t)u4 * 64]; v5 = hwL[(size_t)u5 * 64];
            v6 = hwL[(size_t)u6 * 64]; v7 = hwL[(size_t)u7 * 64];
            acc = fmaf(p0, w0, acc);
            acc = fmaf(p1, w1, acc);
            acc = fmaf(p2, w2, acc);
            acc = fmaf(p3, w3, acc);
            acc = fmaf(p4, w4, acc);
            acc = fmaf(p5, w5, acc);
            acc = fmaf(p6, w6, acc);
            acc = fmaf(p7, w7, acc);
        }
        float outv = acc / dsum + bias[lane];
        if (relu_flag) outv = fmaxf(outv, 0.f);
        hout[(size_t)nd * 64 + lane] = outv;
        return;
    }
    // fallback deg>64 (never expected; correctness only)
    {
        float sdn = sdstA[nd];
        float mx = -INFINITY;
        for (int i = lane; i < deg; i += 64) {
            int p = start + i;
            float sc = ssrc[csr_src[p]] + sdn + elpL[p];
            sc = sc > 0.f ? sc : 0.2f * sc;
            mx = fmaxf(mx, sc);
        }
#pragma unroll
        for (int off = 32; off; off >>= 1) mx = fmaxf(mx, __shfl_xor(mx, off, 64));
        float dsum = 0.f;
        for (int i = lane; i < deg; i += 64) {
            int p = start + i;
            float sc = ssrc[csr_src[p]] + sdn + elpL[p];
            sc = sc > 0.f ? sc : 0.2f * sc;
            dsum += __expf(sc - mx);
        }
#pragma unroll
        for (int off = 32; off; off >>= 1) dsum += __shfl_xor(dsum, off, 64);
        float acc = 0.f;
        for (int i = 0; i < deg; ++i) {
            int p = start + i;
            int s = csr_src[p];
            float sc = ssrc[s] + sdn + elpL[p];
            sc = sc > 0.f ? sc : 0.2f * sc;
            float pex = __expf(sc - mx);
            acc = fmaf(pex, hw[(size_t)s * 64 + lane], acc);
        }
        float outv = acc / dsum + bias[lane];
        if (relu_flag) outv = fmaxf(outv, 0.f);
        hout[(size_t)nd * 64 + lane] = outv;
    }
}

// ---------------- per-layer: softmax + aggregate, 2 nodes per wave ----------------
// Fast path (both degs in [1,32]): two 32-lane groups, lane owns dims
// (2lg, 2lg+1) as float2; 8-deep software-pipelined gathers (R10 form —
// 16-deep regressed via VGPR pressure, and depth-insensitivity shows the
// kernel is at the gather-BW ceiling, not latency-bound). Bit-exact.
__global__ __launch_bounds__(256) void k_row(const float* __restrict__ hw,
                                             const float* __restrict__ ssrc,
                                             const float* __restrict__ sdstA,
                                             const int* __restrict__ csr_src,
                                             const float* __restrict__ elpL,
                                             const int* __restrict__ row_ptr,
                                             const int* __restrict__ counts,
                                             const float* __restrict__ bias,
                                             int relu_flag, float* __restrict__ hout, int n) {
    int wid = threadIdx.x >> 6, lane = threadIdx.x & 63;
    int nd0 = (blockIdx.x * 4 + wid) * 2;
    if (nd0 >= n) return;
    int g = lane >> 5, lg = lane & 31;
    int ndg = nd0 + g;
    bool v1ok = (nd0 + 1) < n;
    int deg_g = (ndg < n) ? counts[ndg] : 0;
    int deg0 = __shfl(deg_g, 0, 64);
    int deg1 = __shfl(deg_g, 32, 64);
    bool fast = v1ok && deg0 >= 1 && deg0 <= 32 && deg1 >= 1 && deg1 <= 32;
    if (fast) {
        int start = row_ptr[ndg];
        float sdn = sdstA[ndg];
        int p = start + lg;
        int s_l = 0;
        float sc = -INFINITY;
        if (lg < deg_g) {
            s_l = csr_src[p];
            sc = ssrc[s_l] + sdn + elpL[p];
            sc = sc > 0.f ? sc : 0.2f * sc;
        }
        float mx = sc;
#pragma unroll
        for (int off = 16; off; off >>= 1) mx = fmaxf(mx, __shfl_xor(mx, off, 64));
        float pe = (lg < deg_g) ? __expf(sc - mx) : 0.f;
        float dsum = pe;
#pragma unroll
        for (int off = 16; off; off >>= 1) dsum += __shfl_xor(dsum, off, 64);
        int degmax = max(deg0, deg1);
        int base = lane & 32;          // group's lane base for broadcasts
        const float2* hw2 = (const float2*)hw;
        float2 acc = make_float2(0.f, 0.f);
        int t0 = __shfl(s_l, base + 0, 64), t1 = __shfl(s_l, base + 1, 64);
        int t2 = __shfl(s_l, base + 2, 64), t3 = __shfl(s_l, base + 3, 64);
        int t4 = __shfl(s_l, base + 4, 64), t5 = __shfl(s_l, base + 5, 64);
        int t6 = __shfl(s_l, base + 6, 64), t7 = __shfl(s_l, base + 7, 64);
        float2 v0 = hw2[(size_t)t0 * 32 + lg], v1 = hw2[(size_t)t1 * 32 + lg];
        float2 v2 = hw2[(size_t)t2 * 32 + lg], v3 = hw2[(size_t)t3 * 32 + lg];
        float2 v4 = hw2[(size_t)t4 * 32 + lg], v5 = hw2[(size_t)t5 * 32 + lg];
        float2 v6 = hw2[(size_t)t6 * 32 + lg], v7 = hw2[(size_t)t7 * 32 + lg];
        for (int i = 0; i < degmax; i += 8) {
            // i+7 <= 31 always (degmax<=32, i multiple of 8 < 32)
            float p0 = __shfl(pe, base + i, 64),     p1 = __shfl(pe, base + i + 1, 64);
            float p2 = __shfl(pe, base + i + 2, 64), p3 = __shfl(pe, base + i + 3, 64);
            float p4 = __shfl(pe, base + i + 4, 64), p5 = __shfl(pe, base + i + 5, 64);
            float p6 = __shfl(pe, base + i + 6, 64), p7 = __shfl(pe, base + i + 7, 64);
            int u0 = __shfl(s_l, base + ((i + 8) & 31), 64);
            int u1 = __shfl(s_l, base + ((i + 9) & 31), 64);
            int u2 = __shfl(s_l, base + ((i + 10) & 31), 64);
            int u3 = __shfl(s_l, base + ((i + 11) & 31), 64);
            int u4 = __shfl(s_l, base + ((i + 12) & 31), 64);
            int u5 = __shfl(s_l, base + ((i + 13) & 31), 64);
            int u6 = __shfl(s_l, base + ((i + 14) & 31), 64);
            int u7 = __shfl(s_l, base + ((i + 15) & 31), 64);
            float2 w0 = v0, w1 = v1, w2 = v2, w3 = v3,
                   w4 = v4, w5 = v5, w6 = v6, w7 = v7;
            v0 = hw2[(size_t)u0 * 32 + lg]; v1 = hw2[(size_t)u1 * 32 + lg];
            v2 = hw2[(size_t)u2 * 32 + lg]; v3 = hw2[(size_t)u3 * 32 + lg];
            v4 = hw2[(size_t)u4 * 32 + lg]; v5 = hw2[(size_t)u5 * 32 + lg];
            v6 = hw2[(size_t)u6 * 32 + lg]; v7 = hw2[(size_t)u7 * 32 + lg];
            acc.x = fmaf(p0, w0.x, acc.x); acc.y = fmaf(p0, w0.y, acc.y);
            acc.x = fmaf(p1, w1.x, acc.x); acc.y = fmaf(p1, w1.y, acc.y);
            acc.x = fmaf(p2, w2.x, acc.x); acc.y = fmaf(p2, w2.y, acc.y);
            acc.x = fmaf(p3, w3.x, acc.x); acc.y = fmaf(p3, w3.y, acc.y);
            acc.x = fmaf(p4, w4.x, acc.x); acc.y = fmaf(p4, w4.y, acc.y);
            acc.x = fmaf(p5, w5.x, acc.x); acc.y = fmaf(p5, w5.y, acc.y);
            acc.x = fmaf(p6, w6.x, acc.x); acc.y = fmaf(p6, w6.y, acc.y);
            acc.x = fmaf(p7, w7.x, acc.x); acc.y = fmaf(p7, w7.y, acc.y);
        }
        float2 bv = ((const float2*)bias)[lg];
        float2 o;
        o.x = acc.x / dsum + bv.x;
        o.y = acc.y / dsum + bv.y;
        if (relu_flag) { o.x = fmaxf(o.x, 0.f); o.y = fmaxf(o.y, 0.f); }
        ((float2*)(hout + (size_t)ndg * 64))[lg] = o;
        return;
    }
    // slow path: whole wave processes each node sequentially (bit-exact)
    for (int q = 0; q < 2; ++q) {
        int nd = nd0 + q;
        if (nd < n)
            row_one_64(nd, lane, hw, ssrc, sdstA, csr_src, elpL, row_ptr, counts,
                       bias, relu_flag, hout);
    }
}

// ---------------- pooling phase A: per-(subchunk, graph) partial sums ----------------
__global__ __launch_bounds__(256) void k_pool_part(const float* __restrict__ h,
                                                   const int* __restrict__ batch,
                                                   float* __restrict__ partial, int n) {
    int g = blockIdx.y, j = blockIdx.x;
    int lo = 0, hi = n;
    while (lo < hi) { int mid = (lo + hi) >> 1; if (batch[mid] < g) lo = mid + 1; else hi = mid; }
    int start = lo;
    lo = start; hi = n;
    while (lo < hi) { int mid = (lo + hi) >> 1; if (batch[mid] < g + 1) lo = mid + 1; else hi = mid; }
    int end = lo;
    int cnt = end - start;
    int chunk = (cnt + PJ - 1) / PJ;
    int clo = start + j * chunk;
    int chi = min(clo + chunk, end);
    int lane = threadIdx.x & 63, q = threadIdx.x >> 6;
    float acc = 0.f;
    for (int nd = clo + q; nd < chi; nd += 4) acc += h[(size_t)nd * 64 + lane];
    __shared__ float s[4][64];
    s[q][lane] = acc;
    __syncthreads();
    if (threadIdx.x < 64) {
        float tot = s[0][threadIdx.x] + s[1][threadIdx.x] + s[2][threadIdx.x] + s[3][threadIdx.x];
        partial[((size_t)g * PJ + j) * 64 + threadIdx.x] = tot;
    }
}

// ---------------- FC with fused pooling phase B ----------------
__global__ __launch_bounds__(256) void k_fc(const float* __restrict__ partial,
                                            const int* __restrict__ batch,
                                            const float* __restrict__ Wfc,
                                            const float* __restrict__ bfc,
                                            float* __restrict__ out, int n) {
    int g = blockIdx.y;
    int c = blockIdx.x * 256 + threadIdx.x;
    __shared__ float sp[64];
    if (threadIdx.x < 64) {
        int d = threadIdx.x;
        float tot = 0.f;
#pragma unroll
        for (int j = 0; j < PJ; ++j) tot += partial[((size_t)g * PJ + j) * 64 + d];
        int lo = 0, hi = n;
        while (lo < hi) { int mid = (lo + hi) >> 1; if (batch[mid] < g) lo = mid + 1; else hi = mid; }
        int start = lo;
        lo = start; hi = n;
        while (lo < hi) { int mid = (lo + hi) >> 1; if (batch[mid] < g + 1) lo = mid + 1; else hi = mid; }
        int cnt = lo - start;
        sp[d] = tot / fmaxf((float)cnt, 1.0f);
    }
    __syncthreads();
    float acc = bfc[c];
#pragma unroll
    for (int k = 0; k < 64; ++k) acc = fmaf(sp[k], Wfc[k * 2048 + c], acc);
    out[(size_t)g * 2048 + c] = acc;
}

extern "C" void kernel_launch(void* const* d_in, const int* in_sizes, int n_in,
                              void* d_out, int out_size, void* d_ws, size_t ws_size,
                              hipStream_t stream) {
    const float* x = (const float*)d_in[0];
    const int* edge_index = (const int*)d_in[1];
    const float* edge_attr = (const float*)d_in[2];
    const int* batch = (const int*)d_in[3];
    const float* W = (const float*)d_in[4];
    const float* a_src = (const float*)d_in[5];
    const float* a_dst = (const float*)d_in[6];
    const float* We = (const float*)d_in[7];
    const float* a_e = (const float*)d_in[8];
    const float* b = (const float*)d_in[9];
    const float* Wfc = (const float*)d_in[10];
    const float* bfc = (const float*)d_in[11];
    float* out = (float*)d_out;

    char* ws = (char*)d_ws;
    size_t off = 0;
    auto alloc = [&](size_t bytes) {
        void* p = ws + off;
        off = (off + bytes + 255) & ~(size_t)255;
        return p;
    };
    float* h0      = (float*)alloc((size_t)NN * 64 * 4);
    float* h1      = (float*)alloc((size_t)NN * 64 * 4);
    float* hw      = (float*)alloc((size_t)NN * 64 * 4);
    float* ssrc    = (float*)alloc((size_t)NN * 4);
    float* sdst    = (float*)alloc((size_t)NN * 4);
    float* el_all  = (float*)alloc((size_t)EE * 16);
    float* elpT    = (float*)alloc((size_t)EE * 4 * 4);   // 4 per-layer scalar planes
    int*   csr_src = (int*)alloc((size_t)EE * 4);
    int*   csr_eid = (int*)alloc((size_t)EE * 4);
    int*   counts  = (int*)alloc((size_t)NN * 4);
    int*   row_ptr = (int*)alloc((size_t)NN * 4);
    int*   cursor  = (int*)alloc((size_t)NN * 4);
    int*   bsum    = (int*)alloc(256 * 4);
    float* partial = (float*)alloc((size_t)GG * PJ * 64 * 4);
    (void)ws_size; (void)in_sizes; (void)n_in; (void)out_size;

    const int* e_src = edge_index;
    const int* e_dst = edge_index + EE;
    const int EB = EE / 256;            // 3125
    const int NB = (NN + 255) / 256;    // 196

    hipMemsetAsync(counts, 0, (size_t)NN * 4, stream);
    hipMemsetAsync(cursor, 0, (size_t)NN * 4, stream);

    k_el<<<EB, 256, 0, stream>>>(edge_attr, We, a_e, el_all, EE);
    k_hist<<<dim3(NXCD, EB), 256, 0, stream>>>(e_dst, counts, EE);
    k_scan1<<<NB, 256, 0, stream>>>(counts, bsum, NN);
    k_scan2<<<1, 256, 0, stream>>>(bsum, NB);
    k_scan3<<<NB, 256, 0, stream>>>(counts, bsum, row_ptr, NN);
    k_fill<<<dim3(NXCD, EB), 256, 0, stream>>>(e_dst, row_ptr, cursor, csr_eid, EE);
    k_sortperm<<<(NN + 7) / 8, 256, 0, stream>>>(csr_eid, e_src, row_ptr, counts,
                                                 (const float4*)el_all, csr_src,
                                                 elpT, elpT + EE, elpT + 2 * (size_t)EE,
                                                 elpT + 3 * (size_t)EE, NN);

    const float* hin = x;
    float* hbufs[2] = {h0, h1};
    for (int l = 0; l < LL; ++l) {
        k_gemm<<<(NN + 63) / 64, 256, 0, stream>>>(hin, W + l * 4096, a_src + l * 64,
                                                   a_dst + l * 64, hw, ssrc, sdst, NN);
        float* hout = hbufs[l & 1];
        k_row<<<(NN + 7) / 8, 256, 0, stream>>>(hw, ssrc, sdst, csr_src,
                                                elpT + (size_t)l * EE, row_ptr, counts,
                                                b + l * 64, (l < LL - 1) ? 1 : 0, hout, NN);
        hin = hout;
    }
    k_pool_part<<<dim3(PJ, GG), 256, 0, stream>>>(hin, batch, partial, NN);
    k_fc<<<dim3(2048 / 256, GG), 256, 0, stream>>>(partial, batch, Wfc, bfc, out, NN);
}